// Round 6
// baseline (197799.194 us; speedup 1.0000x reference)
//
#include <hip/hip_runtime.h>
#include <stdint.h>

// ---------------------------------------------------------------------------
// FastWaveNet autoregressive sampler v4 — persistent pipeline.
//   - weights: 15/32 chunks per lane staged ONCE into LDS (61 KB block),
//     remainder streamed per step via early-issued raw loads (no waitcnt),
//     drained for free by the poll's vmcnt(0)  ->  zero weight latency on
//     the post-poll critical path, and nothing for the compiler to remat.
//   - cross-block records/polls: R5-proven sc0 sc1 stamped 64-bit words.
//   - per-lane arithmetic order bit-identical to R2/R5 (absmax 0.0).
// ---------------------------------------------------------------------------

typedef unsigned long long u64;

#define TT 1024

// byte offsets into d_ws
#define OFF_REC  4096                            // 29 layers * 256 rows * 128 B
#define OFF_SPR  (OFF_REC + 29*256*128)          // 256 rows * 256 u64
#define OFF_HID  (OFF_SPR + 256*256*8)           // 256 stamped hidden
#define OFF_IDX  (OFF_HID + 256*8)               // 1 stamped sampled index
#define OFF_XH   (OFF_IDX + 64)                  // 30*1024*256 f32 x history
#define WS_NEED  ((size_t)OFF_XH + (size_t)30*1024*256*4)

__device__ __forceinline__ long long rt(){
    return (long long)__builtin_amdgcn_s_memrealtime();
}
__device__ __forceinline__ u64 pk(unsigned stamp, float v){
    union { float f; unsigned u; } c; c.f = v;
    return ((u64)stamp << 32) | (u64)c.u;
}
__device__ __forceinline__ u64 pku(unsigned stamp, unsigned v){
    return ((u64)stamp << 32) | (u64)v;
}
__device__ __forceinline__ float uaf(unsigned u){
    union { unsigned u; float f; } c; c.u = u; return c.f;
}
__device__ __forceinline__ unsigned pst(u64 w){ return (unsigned)(w >> 32); }
__device__ __forceinline__ float ldf(const float* p){
    return __hip_atomic_load((float*)p, __ATOMIC_RELAXED, __HIP_MEMORY_SCOPE_AGENT);
}
__device__ __forceinline__ void stf(float* p, float v){
    __hip_atomic_store(p, v, __ATOMIC_RELAXED, __HIP_MEMORY_SCOPE_AGENT);
}

// ---- raw record ops — device-coherent (sc0 sc1), R5-proven ----
__device__ __forceinline__ u64 ld8_s(const void* p){
    u64 r;
    asm volatile("global_load_dwordx2 %0, %1, off sc0 sc1\n\ts_waitcnt vmcnt(0)"
                 : "=&v"(r) : "v"(p) : "memory");
    return r;
}
__device__ __forceinline__ void st8_s(void* p, u64 v){
    asm volatile("global_store_dwordx2 %0, %1, off sc0 sc1" :: "v"(p), "v"(v) : "memory");
}
__device__ __forceinline__ void poll5_s(const void* p, uint4& a, uint4& b, uint4& c,
                                        uint4& d, uint4& e){
    asm volatile(
        "global_load_dwordx4 %0, %5, off sc0 sc1\n\t"
        "global_load_dwordx4 %1, %5, off offset:16 sc0 sc1\n\t"
        "global_load_dwordx4 %2, %5, off offset:32 sc0 sc1\n\t"
        "global_load_dwordx4 %3, %5, off offset:48 sc0 sc1\n\t"
        "global_load_dwordx4 %4, %5, off offset:64 sc0 sc1\n\t"
        "s_waitcnt vmcnt(0)"
        : "=&v"(a),"=&v"(b),"=&v"(c),"=&v"(d),"=&v"(e) : "v"(p) : "memory");
}
__device__ __forceinline__ void poll4_s(const void* p, uint4& a, uint4& b, uint4& c,
                                        uint4& d){
    asm volatile(
        "global_load_dwordx4 %0, %4, off sc0 sc1\n\t"
        "global_load_dwordx4 %1, %4, off offset:16 sc0 sc1\n\t"
        "global_load_dwordx4 %2, %4, off offset:32 sc0 sc1\n\t"
        "global_load_dwordx4 %3, %4, off offset:48 sc0 sc1\n\t"
        "s_waitcnt vmcnt(0)"
        : "=&v"(a),"=&v"(b),"=&v"(c),"=&v"(d) : "v"(p) : "memory");
}
// LDS-only barrier (no vmcnt drain of in-flight global traffic)
__device__ __forceinline__ void bar_lds(){
    asm volatile("s_waitcnt lgkmcnt(0)\n\ts_barrier" ::: "memory");
}

// ---- early-issue streaming: raw loads, NO waitcnt (drained by poll) ----
#define GLV(D,P)  asm volatile("global_load_dwordx4 %0, %1, off" : "=v"(D) : "v"(P) : "memory")
#define GLD1(D,P) asm volatile("global_load_dword %0, %1, off"   : "=v"(D) : "v"(P) : "memory")
#define DRAIN()   asm volatile("s_waitcnt vmcnt(0)" ::: "memory")
#define PIN(X)    asm volatile("" : "+v"(X))

#define FMA4(W,X)   { acc = fmaf((W).x,(X).x,acc); acc = fmaf((W).y,(X).y,acc); \
                      acc = fmaf((W).z,(X).z,acc); acc = fmaf((W).w,(X).w,acc); }
#define FMA4A(A,W,X){ A = fmaf((W).x,(X).x,A); A = fmaf((W).y,(X).y,A); \
                      A = fmaf((W).z,(X).z,A); A = fmaf((W).w,(X).w,A); }

__global__ void __launch_bounds__(256, 1)
wavenet_v4(const float* __restrict__ gy,   const float* __restrict__ gemb,
           const float* __restrict__ gcw,  const float* __restrict__ gwvp,
           const float* __restrict__ gwvx, const float* __restrict__ gwo,
           const float* __restrict__ gwob, const float* __restrict__ gwol,
           const float* __restrict__ gwobl,const float* __restrict__ ge1w,
           const float* __restrict__ ge1b, const float* __restrict__ ge2w,
           const float* __restrict__ ge2b, const float* __restrict__ gsmp,
           int* __restrict__ gout, char* __restrict__ ws)
{
    const int b = blockIdx.x, tid = threadIdx.x;
    const int xcdh = b & 7, kk = b >> 3;
    const int jj = 4*xcdh + (kk >> 3);   // 0..29 layer, 30 head, 31 idle
    const int cc = kk & 7;
    if (jj > 30 || (jj == 30 && cc > 2)) return;

    u64* REC  = (u64*)(ws + OFF_REC);
    u64* SPR  = (u64*)(ws + OFF_SPR);
    u64* HIDP = (u64*)(ws + OFF_HID);
    u64* IDXP = (u64*)(ws + OFF_IDX);
    float* xh = (float*)(ws + OFF_XH);

    __shared__ float4 sW4[15*256];      // 61440 B weight block (role-shared)
    __shared__ float  sTap[256];
    __shared__ float  sXin[256];
    __shared__ float  sY[80];
    __shared__ float  sZ[32];
    __shared__ float  sred[8];
    __shared__ int    sidx[4];

    const long long ddl = rt() + 400000000LL;   // watchdog: wrong, not hung

    // =======================================================================
    if (jj < 30){                                   // ---- layer block ----
        const int j   = jj;
        const int dil = 1 << (j % 10);
        const int q   = tid & 3;
        const int s   = (tid >> 2) & 15;
        const int w   = tid >> 6;
        const int twoq = 2*q;
        const int gr  = (s < 8) ? (32*cc + 8*w + s) : (256 + 32*cc + 8*w + (s - 8));

        const float* rw = (q < 2) ? (gwvp + ((size_t)j*512 + gr)*256 + 128*q)
                                  : (gwvx + ((size_t)j*512 + gr)*256 + 128*(q-2));
        // stage staggered chunks 0..14 into LDS (once)
        #pragma unroll
        for (int k = 0; k < 15; k++)
            sW4[k*256 + tid] = ((const float4*)rw)[(k + twoq) & 31];
        bar_lds();

        const float* cp = gcw + ((size_t)(j*512 + gr))*80 + 20*q;
        const float* w0 = (j < 29) ? (gwo + ((size_t)j*512 + tid)*256 + 32*cc)
                                   : (gwol + (size_t)tid*256 + 32*cc);
        const float* w1 = (j < 29) ? (gwo + ((size_t)j*512 + 256 + tid)*256 + 32*cc)
                                   : w0;
        float bres = 0.f, bskip;
        if (j < 29){ bres = gwob[j*512 + tid]; bskip = gwob[j*512 + 256 + tid]; }
        else       { bskip = gwobl[tid]; }
        PIN(bres); PIN(bskip);

        u64* growp = REC + ((size_t)j*256 + tid)*16;
        const char* pollb = (const char*)(REC + ((size_t)(j>0?j-1:0)*256 + tid)*16);
        u64* sprow = SPR + (size_t)tid*256 + (size_t)j*8 + cc;
        float* xhj = xh + (size_t)j*1024*256;
        float xv_prev = 0.f;

        float4 c0v,c1v,c2v,c3v,c4v;
        float4 v15,v16,v17,v18,v19,v20,v21,v22,v23,v24,v25,v26,v27,v28,v29,v30,v31;
        float4 g0,g1,g2,g3,g4,g5,g6,g7, s0,s1,s2,s3,s4,s5,s6,s7;

        for (int t = 0; t < TT; t++){
            const unsigned stamp = (unsigned)(t + 1);

            // ---- early-issue streams (complete during slack/poll) ----
            GLV(c0v, cp+0);  GLV(c1v, cp+4);  GLV(c2v, cp+8);
            GLV(c3v, cp+12); GLV(c4v, cp+16);
            GLV(v15, rw + 4*((15+twoq)&31)); GLV(v16, rw + 4*((16+twoq)&31));
            GLV(v17, rw + 4*((17+twoq)&31)); GLV(v18, rw + 4*((18+twoq)&31));
            GLV(v19, rw + 4*((19+twoq)&31)); GLV(v20, rw + 4*((20+twoq)&31));
            GLV(v21, rw + 4*((21+twoq)&31)); GLV(v22, rw + 4*((22+twoq)&31));
            GLV(v23, rw + 4*((23+twoq)&31)); GLV(v24, rw + 4*((24+twoq)&31));
            GLV(v25, rw + 4*((25+twoq)&31)); GLV(v26, rw + 4*((26+twoq)&31));
            GLV(v27, rw + 4*((27+twoq)&31)); GLV(v28, rw + 4*((28+twoq)&31));
            GLV(v29, rw + 4*((29+twoq)&31)); GLV(v30, rw + 4*((30+twoq)&31));
            GLV(v31, rw + 4*((31+twoq)&31));
            GLV(g0, w0+0);  GLV(g1, w0+4);  GLV(g2, w0+8);  GLV(g3, w0+12);
            GLV(g4, w0+16); GLV(g5, w0+20); GLV(g6, w0+24); GLV(g7, w0+28);
            if (j < 29){
                GLV(s0, w1+0);  GLV(s1, w1+4);  GLV(s2, w1+8);  GLV(s3, w1+12);
                GLV(s4, w1+16); GLV(s5, w1+20); GLV(s6, w1+24); GLV(s7, w1+28);
            }

            // ---- slack: cond column + dilated tap ----
            if (tid < 80) sY[tid] = gy[tid*TT + t];
            float tapv;
            if (dil == 1) tapv = xv_prev;
            else          tapv = (t >= dil) ? ldf(xhj + (size_t)(t-dil)*256 + tid) : 0.f;
            sTap[tid] = tapv;
            bar_lds();
            DRAIN();                                 // streams + gy + tap done

            float acc = 0.f;
            {
                const float4* yq = (const float4*)(sY + 20*q);
                FMA4(c0v, yq[0]); FMA4(c1v, yq[1]); FMA4(c2v, yq[2]);
                FMA4(c3v, yq[3]); FMA4(c4v, yq[4]);
            }
            if (q < 2){                              // WV_past half: pre-poll
                const float4* xt4 = (const float4*)(sTap + 128*q);
                #pragma unroll
                for (int k = 0; k < 15; k++){
                    float4 wq = sW4[k*256 + tid];
                    FMA4(wq, xt4[(k+twoq)&31]);
                }
                FMA4(v15, xt4[(15+twoq)&31]); FMA4(v16, xt4[(16+twoq)&31]);
                FMA4(v17, xt4[(17+twoq)&31]); FMA4(v18, xt4[(18+twoq)&31]);
                FMA4(v19, xt4[(19+twoq)&31]); FMA4(v20, xt4[(20+twoq)&31]);
                FMA4(v21, xt4[(21+twoq)&31]); FMA4(v22, xt4[(22+twoq)&31]);
                FMA4(v23, xt4[(23+twoq)&31]); FMA4(v24, xt4[(24+twoq)&31]);
                FMA4(v25, xt4[(25+twoq)&31]); FMA4(v26, xt4[(26+twoq)&31]);
                FMA4(v27, xt4[(27+twoq)&31]); FMA4(v28, xt4[(28+twoq)&31]);
                FMA4(v29, xt4[(29+twoq)&31]); FMA4(v30, xt4[(30+twoq)&31]);
                FMA4(v31, xt4[(31+twoq)&31]);
            }

            // ---- poll (one wide-load flight per iteration) ----
            float xv;
            if (j == 0){
                if (t == 0){
                    xv = gemb[127*256 + tid];
                } else {
                    u64 wIdx; int c = 0;
                    do {
                        wIdx = ld8_s(IDXP);
                        if (((++c) & 255) == 0 && rt() > ddl) break;
                    } while (pst(wIdx) != (unsigned)t);
                    const int idx = (int)(wIdx & 0xffffffffu) & 255;
                    xv = gemb[idx*256 + tid];
                }
            } else {
                uint4 r0,r1,r2v,r3v,r4v; bool ok; int c = 0;
                do {
                    poll5_s(pollb, r0,r1,r2v,r3v,r4v);
                    ok = (r0.y==stamp) & (r0.w==stamp) & (r1.y==stamp) & (r1.w==stamp)
                       & (r2v.y==stamp) & (r2v.w==stamp) & (r3v.y==stamp) & (r3v.w==stamp)
                       & (r4v.y==stamp);
                    if (((++c) & 255) == 0 && rt() > ddl) break;
                } while (!ok);
                xv  = uaf(r4v.x);
                xv += uaf(r0.x);  xv += uaf(r0.z);
                xv += uaf(r1.x);  xv += uaf(r1.z);
                xv += uaf(r2v.x); xv += uaf(r2v.z);
                xv += uaf(r3v.x); xv += uaf(r3v.z);
            }
            xv_prev = xv;
            sXin[tid] = xv;
            if (cc == 0){
                if (j <= 28) st8_s(growp + 8, pk(stamp, xv));
                if (dil > 1) stf(&xhj[(size_t)t*256 + tid], xv);
            }
            bar_lds();

            if (q >= 2){                             // WV_present half: post-poll
                const float4* xi4 = (const float4*)(sXin + 128*(q-2));
                #pragma unroll
                for (int k = 0; k < 15; k++){
                    float4 wq = sW4[k*256 + tid];
                    FMA4(wq, xi4[(k+twoq)&31]);
                }
                FMA4(v15, xi4[(15+twoq)&31]); FMA4(v16, xi4[(16+twoq)&31]);
                FMA4(v17, xi4[(17+twoq)&31]); FMA4(v18, xi4[(18+twoq)&31]);
                FMA4(v19, xi4[(19+twoq)&31]); FMA4(v20, xi4[(20+twoq)&31]);
                FMA4(v21, xi4[(21+twoq)&31]); FMA4(v22, xi4[(22+twoq)&31]);
                FMA4(v23, xi4[(23+twoq)&31]); FMA4(v24, xi4[(24+twoq)&31]);
                FMA4(v25, xi4[(25+twoq)&31]); FMA4(v26, xi4[(26+twoq)&31]);
                FMA4(v27, xi4[(27+twoq)&31]); FMA4(v28, xi4[(28+twoq)&31]);
                FMA4(v29, xi4[(29+twoq)&31]); FMA4(v30, xi4[(30+twoq)&31]);
                FMA4(v31, xi4[(31+twoq)&31]);
            }
            acc += __shfl_xor(acc, 1, 64);
            acc += __shfl_xor(acc, 2, 64);
            const float hpart = __shfl_xor(acc, 32, 64);
            if (q == 0 && s < 8)
                sZ[8*w + s] = tanhf(acc) * (1.f/(1.f + expf(-hpart)));
            bar_lds();

            const float4* z4 = (const float4*)sZ;
            if (j < 29){
                float g = 0.f, sk = 0.f;
                FMA4A(g, g0, z4[0]); FMA4A(g, g1, z4[1]); FMA4A(g, g2, z4[2]);
                FMA4A(g, g3, z4[3]); FMA4A(g, g4, z4[4]); FMA4A(g, g5, z4[5]);
                FMA4A(g, g6, z4[6]); FMA4A(g, g7, z4[7]);
                FMA4A(sk, s0, z4[0]); FMA4A(sk, s1, z4[1]); FMA4A(sk, s2, z4[2]);
                FMA4A(sk, s3, z4[3]); FMA4A(sk, s4, z4[4]); FMA4A(sk, s5, z4[5]);
                FMA4A(sk, s6, z4[6]); FMA4A(sk, s7, z4[7]);
                if (cc == 0){ g += bres; sk += bskip; }
                st8_s(growp + cc, pk(stamp, g));
                st8_s(sprow, pk(stamp, sk));
            } else {
                float g = 0.f;
                FMA4A(g, g0, z4[0]); FMA4A(g, g1, z4[1]); FMA4A(g, g2, z4[2]);
                FMA4A(g, g3, z4[3]); FMA4A(g, g4, z4[4]); FMA4A(g, g5, z4[5]);
                FMA4A(g, g6, z4[6]); FMA4A(g, g7, z4[7]);
                if (cc == 0) g += bskip;
                st8_s(sprow, pk(stamp, g));
            }
        }
        return;
    }

    // =======================================================================
    if (jj == 30 && cc < 2){                        // ---- H1: end1 ----
        const int half = cc;
        const int r  = 128*half + (tid >> 1);
        const int hc = tid & 1;
        const float* wp = ge1w + (size_t)r*256 + 128*hc;
        #pragma unroll
        for (int k = 0; k < 15; k++) sW4[k*256 + tid] = ((const float4*)wp)[k];
        bar_lds();
        float b1 = ge1b[r];  PIN(b1);
        const u64* sprb = SPR + (size_t)tid*256;

        float4 e15,e16,e17,e18,e19,e20,e21,e22,e23,e24,e25,e26,e27,e28,e29,e30,e31;

        for (int t = 0; t < TT; t++){
            const unsigned stamp = (unsigned)(t + 1);
            GLV(e15, wp+60);  GLV(e16, wp+64);  GLV(e17, wp+68);  GLV(e18, wp+72);
            GLV(e19, wp+76);  GLV(e20, wp+80);  GLV(e21, wp+84);  GLV(e22, wp+88);
            GLV(e23, wp+92);  GLV(e24, wp+96);  GLV(e25, wp+100); GLV(e26, wp+104);
            GLV(e27, wp+108); GLV(e28, wp+112); GLV(e29, wp+116); GLV(e30, wp+120);
            GLV(e31, wp+124);
            // sum all 240 skip partials, layer-major cc-minor (R2 order)
            float sk = 0.f;
            for (int l = 0; l < 30; l++){
                uint4 r0,r1,r2v,r3v; bool ok; int c = 0;
                const void* p = (const void*)(sprb + l*8);
                do {
                    poll4_s(p, r0,r1,r2v,r3v);
                    ok = (r0.y==stamp)&(r0.w==stamp)&(r1.y==stamp)&(r1.w==stamp)
                       & (r2v.y==stamp)&(r2v.w==stamp)&(r3v.y==stamp)&(r3v.w==stamp);
                    if (((++c) & 255) == 0 && rt() > ddl) break;
                } while (!ok);
                sk += uaf(r0.x);  sk += uaf(r0.z);
                sk += uaf(r1.x);  sk += uaf(r1.z);
                sk += uaf(r2v.x); sk += uaf(r2v.z);
                sk += uaf(r3v.x); sk += uaf(r3v.z);
            }
            sTap[tid] = fmaxf(sk, 0.f);
            bar_lds();
            float a = 0.f;
            const float4* p4 = (const float4*)(sTap + 128*hc);
            #pragma unroll
            for (int k = 0; k < 15; k++){
                float4 wq = sW4[k*256 + tid];
                FMA4A(a, wq, p4[k]);
            }
            FMA4A(a, e15, p4[15]); FMA4A(a, e16, p4[16]); FMA4A(a, e17, p4[17]);
            FMA4A(a, e18, p4[18]); FMA4A(a, e19, p4[19]); FMA4A(a, e20, p4[20]);
            FMA4A(a, e21, p4[21]); FMA4A(a, e22, p4[22]); FMA4A(a, e23, p4[23]);
            FMA4A(a, e24, p4[24]); FMA4A(a, e25, p4[25]); FMA4A(a, e26, p4[26]);
            FMA4A(a, e27, p4[27]); FMA4A(a, e28, p4[28]); FMA4A(a, e29, p4[29]);
            FMA4A(a, e30, p4[30]); FMA4A(a, e31, p4[31]);
            a += __shfl_xor(a, 1, 64);
            if (hc == 0) st8_s(HIDP + r, pk(stamp, fmaxf(a + b1, 0.f)));
            bar_lds();
        }
        return;
    }

    // =======================================================================
    {                                               // ---- H2: end2 + sample ----
        const float* wp = ge2w + (size_t)tid*256;
        #pragma unroll
        for (int k = 0; k < 15; k++) sW4[k*256 + tid] = ((const float4*)wp)[k];
        bar_lds();
        float b2 = ge2b[tid];  PIN(b2);
        const int w = tid >> 6, lane = tid & 63;

        float4 f15,f16,f17,f18,f19,f20,f21,f22,f23,f24,f25,f26,f27,f28,f29,f30,
               f31,f32,f33,f34,f35,f36,f37,f38,f39,f40,f41,f42,f43,f44,f45,f46,
               f47,f48,f49,f50,f51,f52,f53,f54,f55,f56,f57,f58,f59,f60,f61,f62,f63;

        for (int t = 0; t < TT; t++){
            const unsigned stamp = (unsigned)(t + 1);
            GLV(f15, wp+60);  GLV(f16, wp+64);  GLV(f17, wp+68);  GLV(f18, wp+72);
            GLV(f19, wp+76);  GLV(f20, wp+80);  GLV(f21, wp+84);  GLV(f22, wp+88);
            GLV(f23, wp+92);  GLV(f24, wp+96);  GLV(f25, wp+100); GLV(f26, wp+104);
            GLV(f27, wp+108); GLV(f28, wp+112); GLV(f29, wp+116); GLV(f30, wp+120);
            GLV(f31, wp+124); GLV(f32, wp+128); GLV(f33, wp+132); GLV(f34, wp+136);
            GLV(f35, wp+140); GLV(f36, wp+144); GLV(f37, wp+148); GLV(f38, wp+152);
            GLV(f39, wp+156); GLV(f40, wp+160); GLV(f41, wp+164); GLV(f42, wp+168);
            GLV(f43, wp+172); GLV(f44, wp+176); GLV(f45, wp+180); GLV(f46, wp+184);
            GLV(f47, wp+188); GLV(f48, wp+192); GLV(f49, wp+196); GLV(f50, wp+200);
            GLV(f51, wp+204); GLV(f52, wp+208); GLV(f53, wp+212); GLV(f54, wp+216);
            GLV(f55, wp+220); GLV(f56, wp+224); GLV(f57, wp+228); GLV(f58, wp+232);
            GLV(f59, wp+236); GLV(f60, wp+240); GLV(f61, wp+244); GLV(f62, wp+248);
            GLV(f63, wp+252);
            float uu; GLD1(uu, gsmp + t);

            u64 hw; int c = 0;
            do {
                hw = ld8_s(HIDP + tid);
                if (((++c) & 255) == 0 && rt() > ddl) break;
            } while (pst(hw) != stamp);
            sTap[tid] = uaf((unsigned)(hw & 0xffffffffu));
            bar_lds();
            float a = b2;
            const float4* p4 = (const float4*)sTap;
            #pragma unroll
            for (int k = 0; k < 15; k++){
                float4 wq = sW4[k*256 + tid];
                FMA4A(a, wq, p4[k]);
            }
            FMA4A(a, f15, p4[15]); FMA4A(a, f16, p4[16]); FMA4A(a, f17, p4[17]);
            FMA4A(a, f18, p4[18]); FMA4A(a, f19, p4[19]); FMA4A(a, f20, p4[20]);
            FMA4A(a, f21, p4[21]); FMA4A(a, f22, p4[22]); FMA4A(a, f23, p4[23]);
            FMA4A(a, f24, p4[24]); FMA4A(a, f25, p4[25]); FMA4A(a, f26, p4[26]);
            FMA4A(a, f27, p4[27]); FMA4A(a, f28, p4[28]); FMA4A(a, f29, p4[29]);
            FMA4A(a, f30, p4[30]); FMA4A(a, f31, p4[31]); FMA4A(a, f32, p4[32]);
            FMA4A(a, f33, p4[33]); FMA4A(a, f34, p4[34]); FMA4A(a, f35, p4[35]);
            FMA4A(a, f36, p4[36]); FMA4A(a, f37, p4[37]); FMA4A(a, f38, p4[38]);
            FMA4A(a, f39, p4[39]); FMA4A(a, f40, p4[40]); FMA4A(a, f41, p4[41]);
            FMA4A(a, f42, p4[42]); FMA4A(a, f43, p4[43]); FMA4A(a, f44, p4[44]);
            FMA4A(a, f45, p4[45]); FMA4A(a, f46, p4[46]); FMA4A(a, f47, p4[47]);
            FMA4A(a, f48, p4[48]); FMA4A(a, f49, p4[49]); FMA4A(a, f50, p4[50]);
            FMA4A(a, f51, p4[51]); FMA4A(a, f52, p4[52]); FMA4A(a, f53, p4[53]);
            FMA4A(a, f54, p4[54]); FMA4A(a, f55, p4[55]); FMA4A(a, f56, p4[56]);
            FMA4A(a, f57, p4[57]); FMA4A(a, f58, p4[58]); FMA4A(a, f59, p4[59]);
            FMA4A(a, f60, p4[60]); FMA4A(a, f61, p4[61]); FMA4A(a, f62, p4[62]);
            FMA4A(a, f63, p4[63]);
            // softmax + cumsum + first cum > u (identical op order to R2/R5)
            float m = a;
            #pragma unroll
            for (int off = 32; off > 0; off >>= 1) m = fmaxf(m, __shfl_xor(m, off, 64));
            if (lane == 0) sred[w] = m;
            bar_lds();
            m = fmaxf(fmaxf(sred[0], sred[1]), fmaxf(sred[2], sred[3]));
            float pe = expf(a - m);
            float ssum = pe;
            #pragma unroll
            for (int off = 32; off > 0; off >>= 1) ssum += __shfl_xor(ssum, off, 64);
            if (lane == 0) sred[4 + w] = ssum;
            bar_lds();
            const float S = sred[4] + sred[5] + sred[6] + sred[7];
            float cum = pe / S;
            #pragma unroll
            for (int off = 1; off < 64; off <<= 1){
                float vv = __shfl_up(cum, off, 64);
                if (lane >= off) cum += vv;
            }
            if (lane == 63) sred[w] = cum;
            bar_lds();
            float base = 0.f;
            if (w > 0) base += sred[0];
            if (w > 1) base += sred[1];
            if (w > 2) base += sred[2];
            cum += base;
            unsigned long long bal = __ballot(cum > uu);
            int cand = bal ? (w*64 + __ffsll((long long)bal) - 1) : (1 << 30);
            if (lane == 0) sidx[w] = cand;
            bar_lds();
            int idx = min(min(sidx[0], sidx[1]), min(sidx[2], sidx[3]));
            if (idx > 255) idx = 0;
            if (tid == 0){
                gout[t] = idx;
                st8_s(IDXP, pku(stamp, (unsigned)idx));
            }
            bar_lds();
        }
        return;
    }
}

__global__ void ws_too_small_kernel(int* out, int n){
    int i = blockIdx.x*256 + threadIdx.x;
    if (i < n) out[i] = 0;
}

extern "C" void kernel_launch(void* const* d_in, const int* in_sizes, int n_in,
                              void* d_out, int out_size, void* d_ws, size_t ws_size,
                              hipStream_t stream){
    (void)in_sizes; (void)n_in;
    if (ws_size < WS_NEED){
        hipLaunchKernelGGL(ws_too_small_kernel, dim3(4), dim3(256), 0, stream,
                           (int*)d_out, out_size);
        return;
    }
    hipLaunchKernelGGL(wavenet_v4, dim3(256), dim3(256), 0, stream,
                       (const float*)d_in[0],  (const float*)d_in[1],
                       (const float*)d_in[2],  (const float*)d_in[3],
                       (const float*)d_in[4],  (const float*)d_in[5],
                       (const float*)d_in[6],  (const float*)d_in[7],
                       (const float*)d_in[8],  (const float*)d_in[9],
                       (const float*)d_in[10], (const float*)d_in[11],
                       (const float*)d_in[12], (const float*)d_in[13],
                       (int*)d_out, (char*)d_ws);
}